// Round 5
// baseline (143.300 us; speedup 1.0000x reference)
//
#include <hip/hip_runtime.h>

// B=8, H=W=1024, N=4096, R=8 -> d=17, patch=289, out (B,N,578) f32.
// p1[b,n,j] = img1[b, m1 + j%17 - 8, m0 + j/17 - 8]; p2 likewise with (m2,m3).
// normalize each 289-vector: (p - mean) / (std_ddof1 + 1e-4).
//
// R4 post-mortem: kernel ~45us; bytes minimal, conflicts 4%, no pipe >50%.
// R5: 4 pairs per wave (grid-stride) so per-lane invariants (gather slot
// decomposition, phase-2 transpose indices) are computed ONCE and reused 4x,
// plus a 2-stage software pipeline: issue pair i+1's gathers before
// processing pair i -> gather latency hides under reduce/transpose/store.

#define IMG_H 1024
#define IMG_W 1024
#define DPATCH 17
#define NPATCH 289
#define RAD 8
#define LROW 20               // LDS row stride (5 float4 chunks, 16B aligned)
#define PLANE (DPATCH * LROW) // 340 floats per patch plane
#define NPAIRS (8 * 4096)
#define PPW 4                 // pairs per wave
#define NWAVES (NPAIRS / PPW) // 8192

typedef float float4v __attribute__((ext_vector_type(4)));
typedef float float2v __attribute__((ext_vector_type(2)));

__global__ __launch_bounds__(256) void extract_patch_kernel(
    const float* __restrict__ img1,
    const float* __restrict__ img2,
    const int* __restrict__ matches,
    float* __restrict__ out)
{
    __shared__ __align__(16) float lds[4][2 * PLANE];  // per-wave private

    const int lane  = threadIdx.x & 63;
    const int wslot = __builtin_amdgcn_readfirstlane(threadIdx.x >> 6);
    const int wave  = blockIdx.x * 4 + wslot;          // 0 .. 8191
    float* __restrict__ lbase = &lds[wslot][0];

    // ---- per-lane invariants, computed once, reused for all 4 pairs ----
    // gather slots: i=0 -> s=lane (patch1), i=1 -> s=64+lane (mixed at lane 21),
    //               i=2 -> s=128+lane (patch2, lanes 0..41 only)
    int aoff[3], coff[3], ldso[3];
    bool qlt4[3], w2s[3];
#pragma unroll
    for (int i = 0; i < 3; ++i) {
        const int s = lane + (i << 6);
        const bool w2 = (s >= 85);
        int u = w2 ? s - 85 : s;
        if (u >= 85) u = 84;               // slot2 lanes >=42: clamped, unused
        const int a = u / 5, q = u - a * 5;
        aoff[i] = a - RAD;                 // image row offset
        coff[i] = (q << 2) - RAD;          // image col offset of chunk base
        ldso[i] = (w2 ? PLANE : 0) + a * LROW + (q << 2);
        qlt4[i] = (q < 4);                 // chunk q=4 keeps only elem 0
        w2s[i]  = w2;
    }
    const bool v2 = (lane < 42);           // slot2 valid

    // phase-2 transpose indices: out j -> lds[(jj%17)*20 + jj/17] (+plane)
    int p2off[2][4];
    bool p2w2[2][4];
#pragma unroll
    for (int k = 0; k < 2; ++k)
#pragma unroll
        for (int e = 0; e < 4; ++e) {
            const int j  = (k << 8) + (lane << 2) + e;   // 0..511
            const bool w2 = (j >= NPATCH);
            const int jj = w2 ? j - NPATCH : j;
            const int c  = jj / DPATCH;
            const int a  = jj - c * DPATCH;
            p2off[k][e] = (w2 ? PLANE : 0) + a * LROW + c;
            p2w2[k][e]  = w2;
        }
    int pt0 = 0, pt1 = 0;                  // tail j = 512 + 2*lane (+1), patch2
    if (lane < 33) {
        const int jj0 = 512 + (lane << 1) - NPATCH;
        const int c0 = jj0 / DPATCH, a0 = jj0 - c0 * DPATCH;
        const int jj1 = jj0 + 1;
        const int c1 = jj1 / DPATCH, a1 = jj1 - c1 * DPATCH;
        pt0 = PLANE + a0 * LROW + c0;
        pt1 = PLANE + a1 * LROW + c1;
    }

    // ---- issue stage: compute addresses, fire 3 gather loads (no masking) ----
    auto issue = [&](int pair, float4v t[3]) {
        const int4 mm = *(const int4*)(matches + (size_t)pair * 4); // scalar
        const int b = pair >> 12;
        const size_t ioff = (size_t)b * (IMG_H * IMG_W);
        const float* __restrict__ i1 = img1 + ioff;
        const float* __restrict__ i2 = img2 + ioff;
#pragma unroll
        for (int i = 0; i < 3; ++i) {
            const float* __restrict__ ip = w2s[i] ? i2 : i1;
            const int mx = w2s[i] ? mm.z : mm.x;
            const int my = w2s[i] ? mm.w : mm.y;
            const int iy = my + aoff[i];
            const int cb = mx + coff[i];
            float4v vv = {0.f, 0.f, 0.f, 0.f};
            const bool ok = (i != 2) || v2;
            if (ok && (unsigned)iy < IMG_H) {
                if (cb >= 0 && (cb + 3) < IMG_W) {
                    vv = *(const float4v*)(ip + iy * IMG_W + cb);  // dwordx4
                } else {                       // image col-edge (~2% of patches)
                    const float* rp = ip + iy * IMG_W;
#pragma unroll
                    for (int e = 0; e < 4; ++e) {
                        const int ix = cb + e;
                        float v = 0.f;
                        if ((unsigned)ix < IMG_W) v = rp[ix];
                        ((float*)&vv)[e] = v;
                    }
                }
            }
            t[i] = vv;
        }
    };

    // ---- consume stage: mask, stats, reduce, transpose via LDS, store ----
    auto consume = [&](int pair, float4v t[3]) {
        float sA = 0.f, qA = 0.f, sB = 0.f, qB = 0.f;
#pragma unroll
        for (int i = 0; i < 3; ++i) {
            float4v vv = t[i];
            if (!qlt4[i]) { vv.y = 0.f; vv.z = 0.f; vv.w = 0.f; }  // patch col>16
            const float s  = (vv.x + vv.y) + (vv.z + vv.w);
            const float qq = (vv.x * vv.x + vv.y * vv.y)
                           + (vv.z * vv.z + vv.w * vv.w);
            if (w2s[i]) { sB += s; qB += qq; } else { sA += s; qA += qq; }
            if (i != 2 || v2) *(float4v*)(lbase + ldso[i]) = vv;   // 16B LDS
        }

        // wave-64 butterfly (order-independent stats), DS pipe
#pragma unroll
        for (int off = 32; off > 0; off >>= 1) {
            sA += __shfl_xor(sA, off, 64);
            qA += __shfl_xor(qA, off, 64);
            sB += __shfl_xor(sB, off, 64);
            qB += __shfl_xor(qB, off, 64);
        }

        const float meanA = sA * (1.0f / 289.0f);
        float varA = (qA - 289.0f * meanA * meanA) * (1.0f / 288.0f);
        varA = fmaxf(varA, 0.0f);
        const float invA = 1.0f / (sqrtf(varA) + 1e-4f);

        const float meanB = sB * (1.0f / 289.0f);
        float varB = (qB - 289.0f * meanB * meanB) * (1.0f / 288.0f);
        varB = fmaxf(varB, 0.0f);
        const float invB = 1.0f / (sqrtf(varB) + 1e-4f);

        // NO barrier: wave-private buffer, DS ops in-order within a wave.
        float* __restrict__ o = out + (size_t)pair * 578;
#pragma unroll
        for (int k = 0; k < 2; ++k) {
            float4v st;
#pragma unroll
            for (int e = 0; e < 4; ++e) {
                const float v  = lbase[p2off[k][e]];
                const float mn = p2w2[k][e] ? meanB : meanA;
                const float iv = p2w2[k][e] ? invB  : invA;
                ((float*)&st)[e] = (v - mn) * iv;
            }
            __builtin_nontemporal_store(st, (float4v*)(o + (k << 8) + (lane << 2)));
        }
        if (lane < 33) {                   // tail j = 512..577 (66 = 33 x 2)
            float2v st;
            st.x = (lbase[pt0] - meanB) * invB;
            st.y = (lbase[pt1] - meanB) * invB;
            __builtin_nontemporal_store(st, (float2v*)(o + 512 + (lane << 1)));
        }
    };

    // ---- 2-stage pipeline over 4 pairs: issue(i+1) covers consume(i) ----
    float4v tcur[3];
    issue(wave, tcur);
#pragma unroll
    for (int it = 0; it < PPW; ++it) {
        float4v tnxt[3];
        if (it + 1 < PPW) issue(wave + (it + 1) * NWAVES, tnxt);
        consume(wave + it * NWAVES, tcur);
        if (it + 1 < PPW) {
            tcur[0] = tnxt[0]; tcur[1] = tnxt[1]; tcur[2] = tnxt[2];
        }
    }
}

extern "C" void kernel_launch(void* const* d_in, const int* in_sizes, int n_in,
                              void* d_out, int out_size, void* d_ws, size_t ws_size,
                              hipStream_t stream) {
    const float* img1  = (const float*)d_in[0];
    const float* img2  = (const float*)d_in[1];
    const int* matches = (const int*)d_in[2];
    float* out         = (float*)d_out;

    // 8192 waves x 4 pairs each = 32768 pairs; 4 waves/block -> 2048 blocks
    dim3 block(256);
    dim3 grid(NWAVES / 4);
    hipLaunchKernelGGL(extract_patch_kernel, grid, block, 0, stream,
                       img1, img2, matches, out);
}